// Round 1
// baseline (236.690 us; speedup 1.0000x reference)
//
#include <hip/hip_runtime.h>
#include <hip/hip_bf16.h>

// SatelliteSpecificNormalization:
//   x: (B=16, N=8, C=1, H=512, W=512) f32  -> 33,554,432 elems
//   satellite_ids: (B,N)=(16,8) int32 in [-1, 8)
//   weight: (8,1,1,1) f32, bias: (8,1,1,1) f32
//   out = valid ? x*w[sid] + b[sid] : x
//
// Memory-bound: 128 MiB read + 128 MiB write. Strategy: float4 loads/stores
// (16 B/lane), branch-free via per-slab effective (w,b) staged in LDS
// (invalid id -> w=1, b=0). Slab = 2^18 elements = 2^16 float4s.

#define NUM_SLABS 128          // B*N
#define LOG2_VEC_PER_SLAB 16   // (C*H*W)/4 = 65536 float4 per slab

__global__ __launch_bounds__(256) void sat_norm_kernel(
    const float4* __restrict__ x,
    const int* __restrict__ sids,
    const float* __restrict__ weight,
    const float* __restrict__ bias,
    float4* __restrict__ out,
    int n_vec) {
    __shared__ float s_w[NUM_SLABS];
    __shared__ float s_b[NUM_SLABS];
    const int t = threadIdx.x;
    if (t < NUM_SLABS) {
        const int sid = sids[t];
        const bool valid = sid >= 0;
        const int idx = valid ? sid : 0;
        s_w[t] = valid ? weight[idx] : 1.0f;
        s_b[t] = valid ? bias[idx] : 0.0f;
    }
    __syncthreads();

    const int stride = gridDim.x * blockDim.x;
    for (int v = blockIdx.x * blockDim.x + t; v < n_vec; v += stride) {
        const int slab = v >> LOG2_VEC_PER_SLAB;     // same for whole wave (broadcast)
        const float w = s_w[slab];
        const float b = s_b[slab];
        const float4 xv = x[v];
        float4 ov;
        ov.x = fmaf(xv.x, w, b);
        ov.y = fmaf(xv.y, w, b);
        ov.z = fmaf(xv.z, w, b);
        ov.w = fmaf(xv.w, w, b);
        out[v] = ov;
    }
}

extern "C" void kernel_launch(void* const* d_in, const int* in_sizes, int n_in,
                              void* d_out, int out_size, void* d_ws, size_t ws_size,
                              hipStream_t stream) {
    const float4* x      = (const float4*)d_in[0];
    const int*    sids   = (const int*)d_in[1];
    const float*  weight = (const float*)d_in[2];
    const float*  bias   = (const float*)d_in[3];
    float4* out = (float4*)d_out;

    const int n_vec = out_size / 4;                  // 8,388,608 float4s
    const int block = 256;
    int blocks = (n_vec + block - 1) / block;
    if (blocks > 2048) blocks = 2048;                // 256 CU x 8 blocks/CU, grid-stride rest
    sat_norm_kernel<<<blocks, block, 0, stream>>>(x, sids, weight, bias, out, n_vec);
}